// Round 8
// baseline (477.969 us; speedup 1.0000x reference)
//
#include <hip/hip_runtime.h>
#include <hip/hip_bf16.h>
#include <cstdint>
#include <cstddef>

typedef __attribute__((ext_vector_type(8))) short bf16x8;
typedef __attribute__((ext_vector_type(4))) short bf16x4;
typedef __attribute__((ext_vector_type(4))) float f32x4;
typedef __attribute__((ext_vector_type(16))) float f32x16;

#define GLB_AS(p) ((const __attribute__((address_space(1))) void*)(p))
#define LDS_AS(p) ((__attribute__((address_space(3))) void*)(p))

__device__ __forceinline__ short f2bf(float f) {
    union { float f; unsigned u; } x; x.f = f;
    unsigned r = (x.u + 0x7fffu + ((x.u >> 16) & 1u)) >> 16;
    return (short)r;
}
__device__ __forceinline__ unsigned packbf2(float a, float b) {
    union { float f; unsigned u; } x, y; x.f = a; y.f = b;
    return (x.u >> 16) | (y.u & 0xffff0000u);
}
__device__ __forceinline__ f32x4 MF(bf16x8 a, bf16x8 b, f32x4 c) {
    return __builtin_amdgcn_mfma_f32_16x16x32_bf16(a, b, c, 0, 0, 0);
}
__device__ __forceinline__ f32x16 MF32(bf16x8 a, bf16x8 b, f32x16 c) {
    return __builtin_amdgcn_mfma_f32_32x32x16_bf16(a, b, c, 0, 0, 0);
}

// ---------------- weight fp32 -> bf16 cast ----------------
__global__ __launch_bounds__(256) void k_cast_bf16(const float* __restrict__ src,
                                                   short* __restrict__ dst, int n4) {
    int i = blockIdx.x * 256 + threadIdx.x;
    int stride = gridDim.x * 256;
    for (; i < n4; i += stride) {
        float4 v = ((const float4*)src)[i];
        bf16x4 o;
        o[0] = f2bf(v.x); o[1] = f2bf(v.y); o[2] = f2bf(v.z); o[3] = f2bf(v.w);
        ((bf16x4*)dst)[i] = o;
    }
}

// ---------------- LayerNorm (row = 768 fp32) -> bf16 ----------------
__global__ __launch_bounds__(256) void k_layernorm(const float* __restrict__ x,
                                                   const float* __restrict__ w,
                                                   const float* __restrict__ b,
                                                   short* __restrict__ out) {
    const int row = blockIdx.x;
    const int tid = threadIdx.x;
    const float* xr = x + (size_t)row * 768;
    float v0 = xr[tid], v1 = xr[tid + 256], v2 = xr[tid + 512];
    float s = v0 + v1 + v2;
    float ss = v0 * v0 + v1 * v1 + v2 * v2;
    #pragma unroll
    for (int m = 32; m; m >>= 1) { s += __shfl_xor(s, m); ss += __shfl_xor(ss, m); }
    __shared__ float red[8];
    int wid = tid >> 6, lane = tid & 63;
    if (lane == 0) { red[wid] = s; red[4 + wid] = ss; }
    __syncthreads();
    s = red[0] + red[1] + red[2] + red[3];
    ss = red[4] + red[5] + red[6] + red[7];
    float mean = s * (1.f / 768.f);
    float var = ss * (1.f / 768.f) - mean * mean;
    float inv = rsqrtf(var + 1e-5f);
    short* orow = out + (size_t)row * 768;
    orow[tid]       = f2bf((v0 - mean) * inv * w[tid]       + b[tid]);
    orow[tid + 256] = f2bf((v1 - mean) * inv * w[tid + 256] + b[tid + 256]);
    orow[tid + 512] = f2bf((v2 - mean) * inv * w[tid + 512] + b[tid + 512]);
}

// ============ 256x256 GEMM, counted-vmcnt pipeline =============
// A triple-buffered (3x32KB), B double-buffered (2x32KB) = 160KB LDS.
// Per tile t, ph1 issues: stage B(t+1) then stage A(t+2). At ph4:
// outstanding = [B(t+1):4, A(t+2):4] -> vmcnt(4) guarantees B(t+1) and all
// older (incl. A(t+1)) landed while A(t+2) stays in flight across the barrier.
// Wave (wm,wn) only ever reads A-half wm and B-half wn>>1, both guaranteed.
#define QUAD(MB, NB, AA, BB)                                                   \
    do {                                                                       \
        __builtin_amdgcn_s_setprio(1);                                         \
        _Pragma("unroll")                                                      \
        for (int mi = 0; mi < 4; ++mi)                                         \
            _Pragma("unroll")                                                  \
            for (int ni = 0; ni < 2; ++ni) {                                   \
                acc[(MB) + mi][(NB) + ni] =                                    \
                    MF(AA[mi][0], BB[ni][0], acc[(MB) + mi][(NB) + ni]);       \
                acc[(MB) + mi][(NB) + ni] =                                    \
                    MF(AA[mi][1], BB[ni][1], acc[(MB) + mi][(NB) + ni]);       \
            }                                                                  \
        __builtin_amdgcn_s_setprio(0);                                         \
    } while (0)

template <int EPI>
__global__ __launch_bounds__(512, 2) void k_gemm256(const short* __restrict__ A,
                                                    const short* __restrict__ B,
                                                    const float* __restrict__ bias,
                                                    const float* __restrict__ res,
                                                    void* __restrict__ out,
                                                    int M, int N, int K) {
    __shared__ short As3[3][256 * 64];   // 96 KB
    __shared__ short Bs2[2][256 * 64];   // 64 KB
    const int tid = threadIdx.x, lane = tid & 63, wid = tid >> 6;
    const int l4 = lane & 15, lh = lane >> 4;
    const int wm = wid >> 2, wn = wid & 3;
    const int gx = gridDim.x;
    const int nwg = gx * gridDim.y;
    int wg = blockIdx.y * gx + blockIdx.x;
    { const int q = nwg >> 3; wg = (wg & 7) * q + (wg >> 3); }   // nwg % 8 == 0
    const int row0 = (wg / gx) * 256, col0 = (wg % gx) * 256;

    auto stage = [&](const short* __restrict__ src, int base_row, short* lds,
                     int mh, int k0) {
        #pragma unroll
        for (int i = 0; i < 2; ++i) {
            const int chunk = wid * 2 + i;
            const int dl = mh * 16384 + chunk * 1024 + lane * 16;
            const int r = dl >> 7;
            const int cb = (dl & 127) ^ ((r & 7) << 4);
            __builtin_amdgcn_global_load_lds(
                GLB_AS(src + (size_t)(base_row + r) * K + k0 + (cb >> 1)),
                LDS_AS(lds + mh * 8192 + chunk * 512), 16, 0, 0);
        }
    };
    auto rd = [&](const short* lds, int r, int kb) -> bf16x8 {
        return *(const bf16x8*)((const char*)lds + r * 128 +
                                ((kb * 64 + lh * 16) ^ ((r & 7) << 4)));
    };

    f32x4 acc[8][4] = {};
    bf16x8 a[4][2], b0[2][2], b1[2][2];
    const int NT = K >> 6;

    // prologue: A(0), B(0), A(1); wait for A(0)+B(0), keep A(1) in flight
    stage(A, row0, As3[0], 0, 0);  stage(A, row0, As3[0], 1, 0);
    stage(B, col0, Bs2[0], 0, 0);  stage(B, col0, Bs2[0], 1, 0);
    stage(A, row0, As3[1], 0, 64); stage(A, row0, As3[1], 1, 64);
    asm volatile("s_waitcnt vmcnt(4)" ::: "memory");
    __builtin_amdgcn_s_barrier();

    int ia = 0, ia2 = 2, ib = 0;   // buffers for A(t), A(t+2), B(t)
    for (int t = 0; t < NT; ++t) {
        const short* Ac = As3[ia];
        const short* Bc = Bs2[ib];
        const int ib2 = ib ^ 1;
        // ph1: reads quad(0,0) operands; issue B(t+1) then A(t+2)
        #pragma unroll
        for (int mi = 0; mi < 4; ++mi) {
            const int r = wm * 128 + mi * 16 + l4;
            a[mi][0] = rd(Ac, r, 0); a[mi][1] = rd(Ac, r, 1);
        }
        #pragma unroll
        for (int ni = 0; ni < 2; ++ni) {
            const int r = wn * 64 + ni * 16 + l4;
            b0[ni][0] = rd(Bc, r, 0); b0[ni][1] = rd(Bc, r, 1);
        }
        if (t + 1 < NT) {
            const int kn = (t + 1) << 6;
            stage(B, col0, Bs2[ib2], 0, kn);
            stage(B, col0, Bs2[ib2], 1, kn);
        }
        if (t + 2 < NT) {
            const int kn2 = (t + 2) << 6;
            stage(A, row0, As3[ia2], 0, kn2);
            stage(A, row0, As3[ia2], 1, kn2);
        }
        QUAD(0, 0, a, b0);
        __builtin_amdgcn_s_barrier();
        // ph2
        #pragma unroll
        for (int ni = 0; ni < 2; ++ni) {
            const int r = wn * 64 + (2 + ni) * 16 + l4;
            b1[ni][0] = rd(Bc, r, 0); b1[ni][1] = rd(Bc, r, 1);
        }
        QUAD(0, 2, a, b1);
        __builtin_amdgcn_s_barrier();
        // ph3
        #pragma unroll
        for (int mi = 0; mi < 4; ++mi) {
            const int r = wm * 128 + (4 + mi) * 16 + l4;
            a[mi][0] = rd(Ac, r, 0); a[mi][1] = rd(Ac, r, 1);
        }
        QUAD(4, 2, a, b1);
        __builtin_amdgcn_s_barrier();
        // ph4: counted wait — keep A(t+2) in flight
        QUAD(4, 0, a, b0);
        if (t + 2 < NT) {
            asm volatile("s_waitcnt vmcnt(4)" ::: "memory");
        } else if (t + 1 < NT) {
            asm volatile("s_waitcnt vmcnt(0)" ::: "memory");
        }
        __builtin_amdgcn_s_barrier();
        ia = (ia + 1 == 3) ? 0 : ia + 1;
        ia2 = (ia2 + 1 == 3) ? 0 : ia2 + 1;
        ib = ib2;
    }

    // epilogue
    #pragma unroll
    for (int mi = 0; mi < 8; ++mi) {
        const int rowb = row0 + wm * 128 + mi * 16 + lh * 4;
        #pragma unroll
        for (int ni = 0; ni < 4; ++ni) {
            const int col = col0 + wn * 64 + ni * 16 + l4;
            const float bv = bias[col];
            #pragma unroll
            for (int j = 0; j < 4; ++j) {
                const size_t idx = (size_t)(rowb + j) * N + col;
                float v = acc[mi][ni][j] + bv;
                if (EPI == 0) {
                    ((short*)out)[idx] = f2bf(v);
                } else if (EPI == 1) {
                    ((float*)out)[idx] = v + res[idx];
                } else {
                    float u = v + 0.044715f * v * v * v;
                    float t = 1.f - 2.f / (__expf(1.5957691216f * u) + 1.f);
                    ((short*)out)[idx] = f2bf(0.5f * v * (1.f + t));
                }
            }
        }
    }
}

// ---------------- causal flash attention v6 ----------------
// 32x32x16 swapped MFMA, one q-row per lane. Fixed-shift softmax (shift-
// invariant; scores O(1) in exp2 domain), P fed to PV straight from registers.
__global__ __launch_bounds__(256, 2) void k_attn6(const short* __restrict__ qkv,
                                                  short* __restrict__ att) {
    __shared__ short Ks[2][64 * 128];   // 32 KB, rows XOR-swizzled, pad 96->128
    __shared__ short Vs[2][96 * 64];    // 24 KB, V^T swizzled + kv-quad permuted
    const int tid = threadIdx.x, lane = tid & 63, wid = tid >> 6;
    const int lq = lane & 31, hi = lane >> 5;
    const int h = blockIdx.y, b = blockIdx.z;
    const short* base = qkv + (size_t)b * 2048 * 2304 + h * 96;
    const short* Kb = base + 768;
    const short* Vb = base + 1536;
    const int vkvr = (tid / 12) * 4, vd0 = (tid % 12) * 8;
    const int vslot = (vkvr & ~12) | ((vkvr & 4) << 1) | ((vkvr & 8) >> 1);
    bf16x8 vreg[4];
    const float QSC = 0.14724445f; // log2(e)/sqrt(96)

    auto stageK = [&](int jt, int bb) {
        const int kv0 = jt * 64;
        for (int c = wid; c < 16; c += 4) {
            const int dl = c * 1024 + lane * 16;
            const int row = dl >> 8;
            const int scol = (dl & 255) ^ ((row & 7) << 4);
            __builtin_amdgcn_global_load_lds(GLB_AS(Kb + (size_t)(kv0 + row) * 2304 + (scol >> 1)),
                                             LDS_AS(&Ks[bb][c * 512]), 16, 0, 0);
        }
    };
    auto loadV = [&](int jt) {
        if (tid < 192) {
            const int kv0 = jt * 64;
            #pragma unroll
            for (int e = 0; e < 4; ++e)
                vreg[e] = *(const bf16x8*)(Vb + (size_t)(kv0 + vkvr + e) * 2304 + vd0);
        }
    };
    auto writeV = [&](int bb) {
        if (tid < 192) {
            #pragma unroll
            for (int f = 0; f < 8; ++f) {
                const int row = vd0 + f;
                const int sw = ((row & 7) ^ ((row >> 3) & 7)) << 4;
                const int byte = (row * 128 + vslot * 2) ^ sw;
                bf16x4 w4;
                w4[0] = vreg[0][f]; w4[1] = vreg[1][f]; w4[2] = vreg[2][f]; w4[3] = vreg[3][f];
                *(bf16x4*)((char*)&Vs[bb][0] + byte) = w4;
            }
        }
    };

    for (int half = 0; half < 2; ++half) {
        const int qt = half ? 15 - (int)blockIdx.x : (int)blockIdx.x;
        const int q0 = qt * 128 + wid * 32;
        const int qa = q0 + lq;

        bf16x8 qf[6];
        #pragma unroll
        for (int kb = 0; kb < 6; ++kb) {
            bf16x8 v = *(const bf16x8*)(base + (size_t)qa * 2304 + kb * 16 + hi * 8);
            #pragma unroll
            for (int e = 0; e < 8; ++e) {
                union { unsigned u; float f; } x;
                x.u = ((unsigned)(unsigned short)v[e]) << 16;
                qf[kb][e] = f2bf(x.f * QSC);
            }
        }

        f32x16 o[3] = {};
        float lrow = 0.f;
        const int nt = 2 * qt + 2;

        stageK(0, 0);
        loadV(0);
        asm volatile("s_waitcnt vmcnt(0)" ::: "memory");
        writeV(0);
        __syncthreads();

        int cur = 0;
        for (int jt = 0; jt < nt; ++jt) {
            const int nxt = cur ^ 1;
            const bool more = (jt + 1 < nt);
            if (more) { stageK(jt + 1, nxt); loadV(jt + 1); }

            const int kv0 = jt * 64;
            if (kv0 <= q0 + 31) {
                const bool full = (kv0 + 63 <= q0);
                f32x16 s0 = {}, s1 = {};
                #pragma unroll
                for (int kb = 0; kb < 6; ++kb) {
                    const int r0 = lq, r1 = 32 + lq;
                    bf16x8 kf0 = *(const bf16x8*)((const char*)&Ks[cur][0] +
                                  r0 * 256 + ((kb * 32 + hi * 16) ^ ((r0 & 7) << 4)));
                    bf16x8 kf1 = *(const bf16x8*)((const char*)&Ks[cur][0] +
                                  r1 * 256 + ((kb * 32 + hi * 16) ^ ((r1 & 7) << 4)));
                    s0 = MF32(kf0, qf[kb], s0);
                    s1 = MF32(kf1, qf[kb], s1);
                }
                if (!full) {
                    #pragma unroll
                    for (int r = 0; r < 16; ++r) {
                        const int kvl = (r & 3) + 8 * (r >> 2) + 4 * hi;
                        if (kv0 + kvl > qa) s0[r] = -INFINITY;
                        if (kv0 + 32 + kvl > qa) s1[r] = -INFINITY;
                    }
                }
                #pragma unroll
                for (int r = 0; r < 16; ++r) {
                    s0[r] = exp2f(s0[r]);
                    s1[r] = exp2f(s1[r]);
                }
                float ar[16];
                #pragma unroll
                for (int r = 0; r < 16; ++r) ar[r] = s0[r] + s1[r];
                #pragma unroll
                for (int st = 8; st; st >>= 1)
                    #pragma unroll
                    for (int r = 0; r < 8; ++r)
                        if (r < st) ar[r] += ar[r + st];
                lrow += ar[0] + __shfl_xor(ar[0], 32);
                unsigned pk0[8], pk1[8];
                #pragma unroll
                for (int j = 0; j < 8; ++j) {
                    pk0[j] = packbf2(s0[2 * j], s0[2 * j + 1]);
                    pk1[j] = packbf2(s1[2 * j], s1[2 * j + 1]);
                }
                #pragma unroll
                for (int db = 0; db < 3; ++db) {
                    const int vrow = db * 32 + lq;
                    const int vsw = ((vrow & 7) ^ ((vrow >> 3) & 7)) << 4;
                    #pragma unroll
                    for (int c = 0; c < 4; ++c) {
                        bf16x8 vf = *(const bf16x8*)((const char*)&Vs[cur][0] +
                                     vrow * 128 + ((c * 32 + hi * 16) ^ vsw));
                        union { unsigned u[4]; bf16x8 v; } pa;
                        const unsigned* pk = (c < 2) ? pk0 : pk1;
                        const int o4 = (c & 1) * 4;
                        pa.u[0] = pk[o4]; pa.u[1] = pk[o4 + 1];
                        pa.u[2] = pk[o4 + 2]; pa.u[3] = pk[o4 + 3];
                        o[db] = MF32(vf, pa.v, o[db]);
                    }
                }
            }

            if (more) {
                asm volatile("s_waitcnt vmcnt(0)" ::: "memory");
                writeV(nxt);
            }
            __syncthreads();
            cur = nxt;
        }

        const float inv = 1.f / lrow;
        short* orow = att + (size_t)((size_t)b * 2048 + qa) * 768 + h * 96;
        #pragma unroll
        for (int db = 0; db < 3; ++db)
            #pragma unroll
            for (int j = 0; j < 4; ++j) {
                bf16x4 ov;
                #pragma unroll
                for (int e = 0; e < 4; ++e) ov[e] = f2bf(o[db][4 * j + e] * inv);
                *(bf16x4*)(orow + db * 32 + 8 * j + 4 * hi) = ov;
            }
    }
}

// ---------------- launcher ----------------
extern "C" void kernel_launch(void* const* d_in, const int* in_sizes, int n_in,
                              void* d_out, int out_size, void* d_ws, size_t ws_size,
                              hipStream_t stream) {
    (void)in_sizes; (void)n_in; (void)out_size; (void)ws_size;
    const float* x      = (const float*)d_in[0];
    const float* ln1_w  = (const float*)d_in[1];
    const float* ln1_b  = (const float*)d_in[2];
    const float* w_qkv  = (const float*)d_in[3];
    const float* b_qkv  = (const float*)d_in[4];
    const float* w_proj = (const float*)d_in[5];
    const float* b_proj = (const float*)d_in[6];
    const float* ln2_w  = (const float*)d_in[7];
    const float* ln2_b  = (const float*)d_in[8];
    const float* w_fc   = (const float*)d_in[9];
    const float* b_fc   = (const float*)d_in[10];
    const float* w_mlp  = (const float*)d_in[11];
    const float* b_mlp  = (const float*)d_in[12];

    const int C = 768, M = 8 * 2048;

    char* ws = (char*)d_ws;
    size_t off = 0;
    auto alloc = [&](size_t bytes) {
        char* p = ws + off;
        off += (bytes + 255) & ~(size_t)255;
        return p;
    };
    short* wqkv_b = (short*)alloc((size_t)3 * C * C * 2);
    short* wproj_b = (short*)alloc((size_t)C * C * 2);
    short* wfc_b  = (short*)alloc((size_t)4 * C * C * 2);
    short* wmlp_b = (short*)alloc((size_t)4 * C * C * 2);
    short* bufA   = (short*)alloc((size_t)M * C * 2);
    short* bufB   = (short*)alloc((size_t)M * 4 * C * 2);
    float* x2     = (float*)alloc((size_t)M * C * 4);

    k_cast_bf16<<<dim3(432), dim3(256), 0, stream>>>(w_qkv, wqkv_b, 3 * C * C / 4);
    k_cast_bf16<<<dim3(144), dim3(256), 0, stream>>>(w_proj, wproj_b, C * C / 4);
    k_cast_bf16<<<dim3(576), dim3(256), 0, stream>>>(w_fc, wfc_b, 4 * C * C / 4);
    k_cast_bf16<<<dim3(576), dim3(256), 0, stream>>>(w_mlp, wmlp_b, 4 * C * C / 4);

    k_layernorm<<<dim3(M), dim3(256), 0, stream>>>(x, ln1_w, ln1_b, bufA);
    k_gemm256<0><<<dim3(2304 / 256, M / 256), dim3(512), 0, stream>>>(
        bufA, wqkv_b, b_qkv, nullptr, bufB, M, 2304, C);
    k_attn6<<<dim3(8, 8, 8), dim3(256), 0, stream>>>(bufB, bufA);
    k_gemm256<1><<<dim3(C / 256, M / 256), dim3(512), 0, stream>>>(
        bufA, wproj_b, b_proj, x, x2, M, C, C);
    k_layernorm<<<dim3(M), dim3(256), 0, stream>>>(x2, ln2_w, ln2_b, bufA);
    k_gemm256<2><<<dim3(3072 / 256, M / 256), dim3(512), 0, stream>>>(
        bufA, wfc_b, b_fc, nullptr, bufB, M, 3072, C);
    k_gemm256<1><<<dim3(C / 256, M / 256), dim3(512), 0, stream>>>(
        bufB, wmlp_b, b_mlp, x2, d_out, M, C, 4 * C);
}

// Round 9
// 434.755 us; speedup vs baseline: 1.0994x; 1.0994x over previous
//
#include <hip/hip_runtime.h>
#include <hip/hip_bf16.h>
#include <cstdint>
#include <cstddef>

typedef __attribute__((ext_vector_type(8))) short bf16x8;
typedef __attribute__((ext_vector_type(4))) short bf16x4;
typedef __attribute__((ext_vector_type(4))) float f32x4;
typedef __attribute__((ext_vector_type(16))) float f32x16;

#define GLB_AS(p) ((const __attribute__((address_space(1))) void*)(p))
#define LDS_AS(p) ((__attribute__((address_space(3))) void*)(p))

__device__ __forceinline__ short f2bf(float f) {
    union { float f; unsigned u; } x; x.f = f;
    unsigned r = (x.u + 0x7fffu + ((x.u >> 16) & 1u)) >> 16;
    return (short)r;
}
__device__ __forceinline__ unsigned packbf2(float a, float b) {
    union { float f; unsigned u; } x, y; x.f = a; y.f = b;
    return (x.u >> 16) | (y.u & 0xffff0000u);
}
__device__ __forceinline__ f32x4 MF(bf16x8 a, bf16x8 b, f32x4 c) {
    return __builtin_amdgcn_mfma_f32_16x16x32_bf16(a, b, c, 0, 0, 0);
}
__device__ __forceinline__ f32x16 MF32(bf16x8 a, bf16x8 b, f32x16 c) {
    return __builtin_amdgcn_mfma_f32_32x32x16_bf16(a, b, c, 0, 0, 0);
}

// ---------------- fused weight fp32 -> bf16 cast (4 arrays, 1 launch) --------
__global__ __launch_bounds__(256) void k_cast4(const float* __restrict__ s0,
                                               const float* __restrict__ s1,
                                               const float* __restrict__ s2,
                                               const float* __restrict__ s3,
                                               short* __restrict__ d0,
                                               short* __restrict__ d1,
                                               short* __restrict__ d2,
                                               short* __restrict__ d3,
                                               int n0, int n1, int n2, int n3) {
    const int total = n0 + n1 + n2 + n3;   // float4 counts
    int i = blockIdx.x * 256 + threadIdx.x;
    const int stride = gridDim.x * 256;
    for (; i < total; i += stride) {
        int j = i;
        const float* s; short* d;
        if (j < n0) { s = s0; d = d0; }
        else {
            j -= n0;
            if (j < n1) { s = s1; d = d1; }
            else {
                j -= n1;
                if (j < n2) { s = s2; d = d2; }
                else { j -= n2; s = s3; d = d3; }
            }
        }
        float4 v = ((const float4*)s)[j];
        bf16x4 o;
        o[0] = f2bf(v.x); o[1] = f2bf(v.y); o[2] = f2bf(v.z); o[3] = f2bf(v.w);
        ((bf16x4*)d)[j] = o;
    }
}

// ---------------- LayerNorm (row = 768 fp32) -> bf16 ----------------
__global__ __launch_bounds__(256) void k_layernorm(const float* __restrict__ x,
                                                   const float* __restrict__ w,
                                                   const float* __restrict__ b,
                                                   short* __restrict__ out) {
    const int row = blockIdx.x;
    const int tid = threadIdx.x;
    const float* xr = x + (size_t)row * 768;
    float v0 = xr[tid], v1 = xr[tid + 256], v2 = xr[tid + 512];
    float s = v0 + v1 + v2;
    float ss = v0 * v0 + v1 * v1 + v2 * v2;
    #pragma unroll
    for (int m = 32; m; m >>= 1) { s += __shfl_xor(s, m); ss += __shfl_xor(ss, m); }
    __shared__ float red[8];
    int wid = tid >> 6, lane = tid & 63;
    if (lane == 0) { red[wid] = s; red[4 + wid] = ss; }
    __syncthreads();
    s = red[0] + red[1] + red[2] + red[3];
    ss = red[4] + red[5] + red[6] + red[7];
    float mean = s * (1.f / 768.f);
    float var = ss * (1.f / 768.f) - mean * mean;
    float inv = rsqrtf(var + 1e-5f);
    short* orow = out + (size_t)row * 768;
    orow[tid]       = f2bf((v0 - mean) * inv * w[tid]       + b[tid]);
    orow[tid + 256] = f2bf((v1 - mean) * inv * w[tid + 256] + b[tid + 256]);
    orow[tid + 512] = f2bf((v2 - mean) * inv * w[tid + 512] + b[tid + 512]);
}

// ============ 256 x (NFR*64) GEMM: out[m,n] = sum_k A[m,k]*B[n,k] ============
// R7-proven drain schedule: ph1 reads a03/b0 + stages both A halves of t+1,
// ph2 reads b-hi + stages B of t+1, ph4 ends with vmcnt(0). NFR=4 -> BN=256
// (LDS 128KB); NFR=3 -> BN=192 (LDS 112KB) so N=768/2304 grids become exact
// multiples of 256 blocks (granularity fix).
template <int EPI, int NFR>
__global__ __launch_bounds__(512, 2) void k_gemm256(const short* __restrict__ A,
                                                    const short* __restrict__ B,
                                                    const float* __restrict__ bias,
                                                    const float* __restrict__ res,
                                                    void* __restrict__ out,
                                                    int M, int N, int K) {
    __shared__ short As2[2][256 * 64];
    __shared__ short Bs2[2][NFR * 64 * 64];
    const int tid = threadIdx.x, lane = tid & 63, wid = tid >> 6;
    const int l4 = lane & 15, lh = lane >> 4;
    const int wm = wid >> 2, wn = wid & 3;
    const int gx = gridDim.x;
    const int nwg = gx * gridDim.y;
    int wg = blockIdx.y * gx + blockIdx.x;
    { const int q = nwg >> 3; wg = (wg & 7) * q + (wg >> 3); }   // nwg % 8 == 0
    const int row0 = (wg / gx) * 256, col0 = (wg % gx) * (NFR * 64);

    auto stageA = [&](short* lds, int mh, int k0) {
        #pragma unroll
        for (int i = 0; i < 2; ++i) {
            const int chunk = wid * 2 + i;
            const int dl = mh * 16384 + chunk * 1024 + lane * 16;
            const int r = dl >> 7;
            const int cb = (dl & 127) ^ ((r & 7) << 4);
            __builtin_amdgcn_global_load_lds(
                GLB_AS(A + (size_t)(row0 + r) * K + k0 + (cb >> 1)),
                LDS_AS(lds + mh * 8192 + chunk * 512), 16, 0, 0);
        }
    };
    auto stageB = [&](short* lds, int k0) {
        #pragma unroll
        for (int i = 0; i < NFR; ++i) {
            const int chunk = wid * NFR + i;
            const int dl = chunk * 1024 + lane * 16;
            const int r = dl >> 7;
            const int cb = (dl & 127) ^ ((r & 7) << 4);
            __builtin_amdgcn_global_load_lds(
                GLB_AS(B + (size_t)(col0 + r) * K + k0 + (cb >> 1)),
                LDS_AS(lds + chunk * 512), 16, 0, 0);
        }
    };
    auto rd = [&](const short* lds, int r, int kb) -> bf16x8 {
        return *(const bf16x8*)((const char*)lds + r * 128 +
                                ((kb * 64 + lh * 16) ^ ((r & 7) << 4)));
    };

    f32x4 acc[8][NFR] = {};
    bf16x8 a[4][2], b0[2][2], b1[2][2];
    const int NT = K >> 6;

    stageA(As2[0], 0, 0);
    stageA(As2[0], 1, 0);
    stageB(Bs2[0], 0);
    asm volatile("s_waitcnt vmcnt(0)" ::: "memory");
    __builtin_amdgcn_s_barrier();

    for (int t = 0; t < NT; ++t) {
        const int cur = t & 1, nxt = cur ^ 1;
        const short* Ac = As2[cur];
        const short* Bc = Bs2[cur];
        const int kn = (t + 1) << 6;
        const bool more = (t + 1 < NT);
        // ph1: quad(lo-M, lo-N); stage both A halves of t+1
        #pragma unroll
        for (int mi = 0; mi < 4; ++mi) {
            const int r = wm * 128 + mi * 16 + l4;
            a[mi][0] = rd(Ac, r, 0); a[mi][1] = rd(Ac, r, 1);
        }
        #pragma unroll
        for (int ni = 0; ni < 2; ++ni) {
            const int r = wn * (NFR * 16) + ni * 16 + l4;
            b0[ni][0] = rd(Bc, r, 0); b0[ni][1] = rd(Bc, r, 1);
        }
        if (more) { stageA(As2[nxt], 0, kn); stageA(As2[nxt], 1, kn); }
        __builtin_amdgcn_s_setprio(1);
        #pragma unroll
        for (int mi = 0; mi < 4; ++mi)
            #pragma unroll
            for (int ni = 0; ni < 2; ++ni) {
                acc[mi][ni] = MF(a[mi][0], b0[ni][0], acc[mi][ni]);
                acc[mi][ni] = MF(a[mi][1], b0[ni][1], acc[mi][ni]);
            }
        __builtin_amdgcn_s_setprio(0);
        __builtin_amdgcn_s_barrier();
        // ph2: quad(lo-M, hi-N); stage B of t+1
        #pragma unroll
        for (int j = 0; j < NFR - 2; ++j) {
            const int r = wn * (NFR * 16) + (2 + j) * 16 + l4;
            b1[j][0] = rd(Bc, r, 0); b1[j][1] = rd(Bc, r, 1);
        }
        if (more) stageB(Bs2[nxt], kn);
        __builtin_amdgcn_s_setprio(1);
        #pragma unroll
        for (int mi = 0; mi < 4; ++mi)
            #pragma unroll
            for (int j = 0; j < NFR - 2; ++j) {
                acc[mi][2 + j] = MF(a[mi][0], b1[j][0], acc[mi][2 + j]);
                acc[mi][2 + j] = MF(a[mi][1], b1[j][1], acc[mi][2 + j]);
            }
        __builtin_amdgcn_s_setprio(0);
        __builtin_amdgcn_s_barrier();
        // ph3: quad(hi-M, hi-N)
        #pragma unroll
        for (int mi = 0; mi < 4; ++mi) {
            const int r = wm * 128 + (4 + mi) * 16 + l4;
            a[mi][0] = rd(Ac, r, 0); a[mi][1] = rd(Ac, r, 1);
        }
        __builtin_amdgcn_s_setprio(1);
        #pragma unroll
        for (int mi = 0; mi < 4; ++mi)
            #pragma unroll
            for (int j = 0; j < NFR - 2; ++j) {
                acc[4 + mi][2 + j] = MF(a[mi][0], b1[j][0], acc[4 + mi][2 + j]);
                acc[4 + mi][2 + j] = MF(a[mi][1], b1[j][1], acc[4 + mi][2 + j]);
            }
        __builtin_amdgcn_s_setprio(0);
        __builtin_amdgcn_s_barrier();
        // ph4: quad(hi-M, lo-N); drain staging of t+1
        __builtin_amdgcn_s_setprio(1);
        #pragma unroll
        for (int mi = 0; mi < 4; ++mi)
            #pragma unroll
            for (int ni = 0; ni < 2; ++ni) {
                acc[4 + mi][ni] = MF(a[mi][0], b0[ni][0], acc[4 + mi][ni]);
                acc[4 + mi][ni] = MF(a[mi][1], b0[ni][1], acc[4 + mi][ni]);
            }
        __builtin_amdgcn_s_setprio(0);
        asm volatile("s_waitcnt vmcnt(0)" ::: "memory");
        __builtin_amdgcn_s_barrier();
    }

    // epilogue
    #pragma unroll
    for (int mi = 0; mi < 8; ++mi) {
        const int rowb = row0 + wm * 128 + mi * 16 + lh * 4;
        #pragma unroll
        for (int ni = 0; ni < NFR; ++ni) {
            const int col = col0 + wn * (NFR * 16) + ni * 16 + l4;
            const float bv = bias[col];
            #pragma unroll
            for (int j = 0; j < 4; ++j) {
                const size_t idx = (size_t)(rowb + j) * N + col;
                float v = acc[mi][ni][j] + bv;
                if (EPI == 0) {
                    ((short*)out)[idx] = f2bf(v);
                } else if (EPI == 1) {
                    ((float*)out)[idx] = v + res[idx];
                } else {
                    float u = v + 0.044715f * v * v * v;
                    float t = 1.f - 2.f / (__expf(1.5957691216f * u) + 1.f);
                    ((short*)out)[idx] = f2bf(0.5f * v * (1.f + t));
                }
            }
        }
    }
}

// ---------------- causal flash attention v6 (unchanged from R7) ----------------
__global__ __launch_bounds__(256, 2) void k_attn6(const short* __restrict__ qkv,
                                                  short* __restrict__ att) {
    __shared__ short Ks[2][64 * 128];   // 32 KB, rows XOR-swizzled, pad 96->128
    __shared__ short Vs[2][96 * 64];    // 24 KB, V^T swizzled + kv-quad permuted
    const int tid = threadIdx.x, lane = tid & 63, wid = tid >> 6;
    const int lq = lane & 31, hi = lane >> 5;
    const int h = blockIdx.y, b = blockIdx.z;
    const short* base = qkv + (size_t)b * 2048 * 2304 + h * 96;
    const short* Kb = base + 768;
    const short* Vb = base + 1536;
    const int vkvr = (tid / 12) * 4, vd0 = (tid % 12) * 8;
    const int vslot = (vkvr & ~12) | ((vkvr & 4) << 1) | ((vkvr & 8) >> 1);
    bf16x8 vreg[4];
    const float QSC = 0.14724445f; // log2(e)/sqrt(96)

    auto stageK = [&](int jt, int bb) {
        const int kv0 = jt * 64;
        for (int c = wid; c < 16; c += 4) {
            const int dl = c * 1024 + lane * 16;
            const int row = dl >> 8;
            const int scol = (dl & 255) ^ ((row & 7) << 4);
            __builtin_amdgcn_global_load_lds(GLB_AS(Kb + (size_t)(kv0 + row) * 2304 + (scol >> 1)),
                                             LDS_AS(&Ks[bb][c * 512]), 16, 0, 0);
        }
    };
    auto loadV = [&](int jt) {
        if (tid < 192) {
            const int kv0 = jt * 64;
            #pragma unroll
            for (int e = 0; e < 4; ++e)
                vreg[e] = *(const bf16x8*)(Vb + (size_t)(kv0 + vkvr + e) * 2304 + vd0);
        }
    };
    auto writeV = [&](int bb) {
        if (tid < 192) {
            #pragma unroll
            for (int f = 0; f < 8; ++f) {
                const int row = vd0 + f;
                const int sw = ((row & 7) ^ ((row >> 3) & 7)) << 4;
                const int byte = (row * 128 + vslot * 2) ^ sw;
                bf16x4 w4;
                w4[0] = vreg[0][f]; w4[1] = vreg[1][f]; w4[2] = vreg[2][f]; w4[3] = vreg[3][f];
                *(bf16x4*)((char*)&Vs[bb][0] + byte) = w4;
            }
        }
    };

    for (int half = 0; half < 2; ++half) {
        const int qt = half ? 15 - (int)blockIdx.x : (int)blockIdx.x;
        const int q0 = qt * 128 + wid * 32;
        const int qa = q0 + lq;

        bf16x8 qf[6];
        #pragma unroll
        for (int kb = 0; kb < 6; ++kb) {
            bf16x8 v = *(const bf16x8*)(base + (size_t)qa * 2304 + kb * 16 + hi * 8);
            #pragma unroll
            for (int e = 0; e < 8; ++e) {
                union { unsigned u; float f; } x;
                x.u = ((unsigned)(unsigned short)v[e]) << 16;
                qf[kb][e] = f2bf(x.f * QSC);
            }
        }

        f32x16 o[3] = {};
        float lrow = 0.f;
        const int nt = 2 * qt + 2;

        stageK(0, 0);
        loadV(0);
        asm volatile("s_waitcnt vmcnt(0)" ::: "memory");
        writeV(0);
        __syncthreads();

        int cur = 0;
        for (int jt = 0; jt < nt; ++jt) {
            const int nxt = cur ^ 1;
            const bool more = (jt + 1 < nt);
            if (more) { stageK(jt + 1, nxt); loadV(jt + 1); }

            const int kv0 = jt * 64;
            if (kv0 <= q0 + 31) {
                const bool full = (kv0 + 63 <= q0);
                f32x16 s0 = {}, s1 = {};
                #pragma unroll
                for (int kb = 0; kb < 6; ++kb) {
                    const int r0 = lq, r1 = 32 + lq;
                    bf16x8 kf0 = *(const bf16x8*)((const char*)&Ks[cur][0] +
                                  r0 * 256 + ((kb * 32 + hi * 16) ^ ((r0 & 7) << 4)));
                    bf16x8 kf1 = *(const bf16x8*)((const char*)&Ks[cur][0] +
                                  r1 * 256 + ((kb * 32 + hi * 16) ^ ((r1 & 7) << 4)));
                    s0 = MF32(kf0, qf[kb], s0);
                    s1 = MF32(kf1, qf[kb], s1);
                }
                if (!full) {
                    #pragma unroll
                    for (int r = 0; r < 16; ++r) {
                        const int kvl = (r & 3) + 8 * (r >> 2) + 4 * hi;
                        if (kv0 + kvl > qa) s0[r] = -INFINITY;
                        if (kv0 + 32 + kvl > qa) s1[r] = -INFINITY;
                    }
                }
                #pragma unroll
                for (int r = 0; r < 16; ++r) {
                    s0[r] = exp2f(s0[r]);
                    s1[r] = exp2f(s1[r]);
                }
                float ar[16];
                #pragma unroll
                for (int r = 0; r < 16; ++r) ar[r] = s0[r] + s1[r];
                #pragma unroll
                for (int st = 8; st; st >>= 1)
                    #pragma unroll
                    for (int r = 0; r < 8; ++r)
                        if (r < st) ar[r] += ar[r + st];
                lrow += ar[0] + __shfl_xor(ar[0], 32);
                unsigned pk0[8], pk1[8];
                #pragma unroll
                for (int j = 0; j < 8; ++j) {
                    pk0[j] = packbf2(s0[2 * j], s0[2 * j + 1]);
                    pk1[j] = packbf2(s1[2 * j], s1[2 * j + 1]);
                }
                #pragma unroll
                for (int db = 0; db < 3; ++db) {
                    const int vrow = db * 32 + lq;
                    const int vsw = ((vrow & 7) ^ ((vrow >> 3) & 7)) << 4;
                    #pragma unroll
                    for (int c = 0; c < 4; ++c) {
                        bf16x8 vf = *(const bf16x8*)((const char*)&Vs[cur][0] +
                                     vrow * 128 + ((c * 32 + hi * 16) ^ vsw));
                        union { unsigned u[4]; bf16x8 v; } pa;
                        const unsigned* pk = (c < 2) ? pk0 : pk1;
                        const int o4 = (c & 1) * 4;
                        pa.u[0] = pk[o4]; pa.u[1] = pk[o4 + 1];
                        pa.u[2] = pk[o4 + 2]; pa.u[3] = pk[o4 + 3];
                        o[db] = MF32(vf, pa.v, o[db]);
                    }
                }
            }

            if (more) {
                asm volatile("s_waitcnt vmcnt(0)" ::: "memory");
                writeV(nxt);
            }
            __syncthreads();
            cur = nxt;
        }

        const float inv = 1.f / lrow;
        short* orow = att + (size_t)((size_t)b * 2048 + qa) * 768 + h * 96;
        #pragma unroll
        for (int db = 0; db < 3; ++db)
            #pragma unroll
            for (int j = 0; j < 4; ++j) {
                bf16x4 ov;
                #pragma unroll
                for (int e = 0; e < 4; ++e) ov[e] = f2bf(o[db][4 * j + e] * inv);
                *(bf16x4*)(orow + db * 32 + 8 * j + 4 * hi) = ov;
            }
    }
}

// ---------------- launcher ----------------
extern "C" void kernel_launch(void* const* d_in, const int* in_sizes, int n_in,
                              void* d_out, int out_size, void* d_ws, size_t ws_size,
                              hipStream_t stream) {
    (void)in_sizes; (void)n_in; (void)out_size; (void)ws_size;
    const float* x      = (const float*)d_in[0];
    const float* ln1_w  = (const float*)d_in[1];
    const float* ln1_b  = (const float*)d_in[2];
    const float* w_qkv  = (const float*)d_in[3];
    const float* b_qkv  = (const float*)d_in[4];
    const float* w_proj = (const float*)d_in[5];
    const float* b_proj = (const float*)d_in[6];
    const float* ln2_w  = (const float*)d_in[7];
    const float* ln2_b  = (const float*)d_in[8];
    const float* w_fc   = (const float*)d_in[9];
    const float* b_fc   = (const float*)d_in[10];
    const float* w_mlp  = (const float*)d_in[11];
    const float* b_mlp  = (const float*)d_in[12];

    const int C = 768, M = 8 * 2048;

    char* ws = (char*)d_ws;
    size_t off = 0;
    auto alloc = [&](size_t bytes) {
        char* p = ws + off;
        off += (bytes + 255) & ~(size_t)255;
        return p;
    };
    short* wqkv_b = (short*)alloc((size_t)3 * C * C * 2);
    short* wproj_b = (short*)alloc((size_t)C * C * 2);
    short* wfc_b  = (short*)alloc((size_t)4 * C * C * 2);
    short* wmlp_b = (short*)alloc((size_t)4 * C * C * 2);
    short* bufA   = (short*)alloc((size_t)M * C * 2);
    short* bufB   = (short*)alloc((size_t)M * 4 * C * 2);
    float* x2     = (float*)alloc((size_t)M * C * 4);

    // one fused weight-cast launch
    k_cast4<<<dim3(1728), dim3(256), 0, stream>>>(
        w_qkv, w_proj, w_fc, w_mlp, wqkv_b, wproj_b, wfc_b, wmlp_b,
        3 * C * C / 4, C * C / 4, 4 * C * C / 4, 4 * C * C / 4);

    k_layernorm<<<dim3(M), dim3(256), 0, stream>>>(x, ln1_w, ln1_b, bufA);
    // qkv: N=2304, BN=192 -> grid 12x64 = 768 blocks (3 exact rounds)
    k_gemm256<0, 3><<<dim3(2304 / 192, M / 256), dim3(512), 0, stream>>>(
        bufA, wqkv_b, b_qkv, nullptr, bufB, M, 2304, C);
    k_attn6<<<dim3(8, 8, 8), dim3(256), 0, stream>>>(bufB, bufA);
    // attn-proj: N=768, BN=192 -> grid 4x64 = 256 blocks (1 exact round)
    k_gemm256<1, 3><<<dim3(768 / 192, M / 256), dim3(512), 0, stream>>>(
        bufA, wproj_b, b_proj, x, x2, M, C, C);
    k_layernorm<<<dim3(M), dim3(256), 0, stream>>>(x2, ln2_w, ln2_b, bufA);
    // fc: N=3072, BN=256 -> grid 12x64 = 768 blocks (3 exact rounds)
    k_gemm256<2, 4><<<dim3(3072 / 256, M / 256), dim3(512), 0, stream>>>(
        bufA, wfc_b, b_fc, nullptr, bufB, M, 3072, C);
    // mlp-proj: N=768, BN=192 -> grid 4x64 = 256 blocks (1 exact round)
    k_gemm256<1, 3><<<dim3(768 / 192, M / 256), dim3(512), 0, stream>>>(
        bufB, wmlp_b, b_mlp, x2, d_out, M, C, 4 * C);
}